// Round 15
// baseline (462.844 us; speedup 1.0000x reference)
//
#include <hip/hip_runtime.h>
#include <math.h>

#define NB_B 512
#define NE 100000
#define NE_PAD 100032   // 3126 tiles x 32 rows (pad rows 100000..100031 zero)
#define DD 200
#define CC 32
#define FCIN 10368   // 32*18*18
#define HW 324       // 18*18
#define BNEPS 1e-5f
#define KP 224       // scores K padded to multiple of 32 for MFMA

#define ENT_BLKS 10941   // 100032*28/256 exactly
#define FCW_BLKS 1013
#define GATH_OFF (ENT_BLKS + FCW_BLKS)   // 11954

typedef __attribute__((ext_vector_type(8))) short short8;   // 8 bf16 = 4 VGPRs
typedef __attribute__((ext_vector_type(4))) float floatx4;  // MFMA acc

// dacc (double) slots:
// 0: bn0 sum, 1: bn0 sumsq (also l2 for h_e+r_e)
// 2..33: bn1 per-channel sum, 34..65: bn1 per-channel sumsq
// 67: fc_w sumsq, 68: softplus sum (incl. pad constant), 69: scores sum, 70: pos-scores sum

static __device__ __forceinline__ float blk_reduce(float v, volatile float* sbuf) {
  for (int o = 32; o > 0; o >>= 1) v += __shfl_down(v, o, 64);
  int lane = threadIdx.x & 63, wid = threadIdx.x >> 6;
  if (lane == 0) sbuf[wid] = v;
  __syncthreads();
  float r = 0.f;
  int nw = (blockDim.x + 63) >> 6;
  if ((int)threadIdx.x < nw) r = sbuf[threadIdx.x];
  if (threadIdx.x < 64) {
    for (int o = 32; o > 0; o >>= 1) r += __shfl_down(r, o, 64);
  }
  __syncthreads();
  return r;  // valid on thread 0
}

static __device__ __forceinline__ unsigned short f32_to_bf16(float f) {
  unsigned int u = __float_as_uint(f);
  u += 0x7fffu + ((u >> 16) & 1u);  // round-to-nearest-even
  return (unsigned short)(u >> 16);
}
static __device__ __forceinline__ float bf16_to_f32(unsigned short b) {
  return __uint_as_float(((unsigned int)b) << 16);
}

// K1: fused prep (3-branch). Blocks [0,ENT_BLKS): entity f32->bf16 into entb in
// TILED CHUNK-MAJOR layout: tile=row/32, rr=row%32, chunk c=col8; short offset
// = tile*7168 + c*256 + rr*8 (byte = tile*14336 + c*512 + rr*16). This makes
// the scores-kernel gload_lds write linear AND the ds_read_b128 pattern
// conflict-free (quad reads one contiguous 256B range). ent reads coalesced.
// [ENT_BLKS,GATH_OFF): fc_w -> bf16 + sumsq. [GATH_OFF,+512): gather, bn0.
__global__ __launch_bounds__(256) void k_cvt(const float* __restrict__ ent,
                                             unsigned short* __restrict__ entb,
                                             const float* __restrict__ fcw,
                                             unsigned short* __restrict__ fcwb,
                                             const float* __restrict__ rel,
                                             const int* __restrict__ h,
                                             const int* __restrict__ r,
                                             float* __restrict__ x0,
                                             double* dacc) {
  if (blockIdx.x < ENT_BLKS) {
    int g = blockIdx.x * 256 + threadIdx.x;   // 0 .. 2,800,895  (100032*28)
    int row = g / 28;
    int c = g - row * 28;                     // chunk 0..27
    int c8 = c * 8;
    short8 o;
    if (c8 < 200 && row < NE) {
      const float4* s = (const float4*)(ent + (long)row * DD + c8);
      float4 u = s[0], v = s[1];
      o[0] = (short)f32_to_bf16(u.x); o[1] = (short)f32_to_bf16(u.y);
      o[2] = (short)f32_to_bf16(u.z); o[3] = (short)f32_to_bf16(u.w);
      o[4] = (short)f32_to_bf16(v.x); o[5] = (short)f32_to_bf16(v.y);
      o[6] = (short)f32_to_bf16(v.z); o[7] = (short)f32_to_bf16(v.w);
    } else {
      o = (short8){0, 0, 0, 0, 0, 0, 0, 0};
    }
    int tile = row >> 5, rr = row & 31;
    *(short8*)(entb + (long)tile * 7168 + c * 256 + rr * 8) = o;
  } else if (blockIdx.x < GATH_OFF) {
    int g = (blockIdx.x - ENT_BLKS) * 256 + threadIdx.x;   // x8 elems
    float sq = 0.f;
    if (g < 259200) {
      const float4* s = (const float4*)(fcw + (long)g * 8);
      float4 u = s[0], v = s[1];
      sq = u.x*u.x + u.y*u.y + u.z*u.z + u.w*u.w
         + v.x*v.x + v.y*v.y + v.z*v.z + v.w*v.w;
      ushort4 o0, o1;
      o0.x = f32_to_bf16(u.x); o0.y = f32_to_bf16(u.y);
      o0.z = f32_to_bf16(u.z); o0.w = f32_to_bf16(u.w);
      o1.x = f32_to_bf16(v.x); o1.y = f32_to_bf16(v.y);
      o1.z = f32_to_bf16(v.z); o1.w = f32_to_bf16(v.w);
      ushort4* d = (ushort4*)(fcwb + (long)g * 8);
      d[0] = o0; d[1] = o1;
    }
    __shared__ float sbuf[8];
    float tq = blk_reduce(sq, sbuf);
    if (threadIdx.x == 0) atomicAdd(&dacc[67], (double)tq);
  } else {
    int b = blockIdx.x - GATH_OFF;
    int hi = h[b], ri = r[b];
    float s = 0.f, sq = 0.f;
    for (int i = threadIdx.x; i < 400; i += 256) {
      float v = (i < 200) ? ent[(long)hi * DD + i] : rel[(long)ri * DD + (i - 200)];
      x0[b * 400 + i] = v;
      s += v; sq += v * v;
    }
    __shared__ float sbuf[8];
    float ts = blk_reduce(s, sbuf);
    float tq = blk_reduce(sq, sbuf);
    if (threadIdx.x == 0) {
      atomicAdd(&dacc[0], (double)ts);
      atomicAdd(&dacc[1], (double)tq);
    }
  }
}

// K2: bn0 + conv3x3 + conv_b -> yb bf16 [512 x 10368] (pre-bn1); bn1 stats (f32)
__global__ __launch_bounds__(256) void k_conv(const float* __restrict__ x0,
                       const float* __restrict__ convw, const float* __restrict__ convb,
                       const float* __restrict__ g0, const float* __restrict__ b0,
                       unsigned short* __restrict__ yb, double* dacc) {
  __shared__ float xs[400], wsm[288], cbs[32], ssum[32], ssq[32];
  __shared__ float a0s, s0s;
  int b = blockIdx.x, t = threadIdx.x;
  for (int i = t; i < 400; i += 256) xs[i] = x0[b * 400 + i];
  for (int i = t; i < 288; i += 256) wsm[i] = convw[i];
  if (t < 32) cbs[t] = convb[t];
  if (t == 0) {
    double m = dacc[0] / 204800.0;
    double v = dacc[1] / 204800.0 - m * m;
    float a = g0[0] * rsqrtf((float)v + BNEPS);
    a0s = a; s0s = b0[0] - (float)m * a;
  }
  __syncthreads();
  float a0 = a0s, s0 = s0s;
  for (int i = t; i < 400; i += 256) xs[i] = a0 * xs[i] + s0;
  __syncthreads();
  int c = t >> 3, sub = t & 7;
  const float* w = &wsm[c * 9];
  float cb = cbs[c];
  float s = 0.f, sq = 0.f;
  for (int e = sub; e < HW; e += 8) {
    int oh = e / 18, ow = e - oh * 18;
    const float* xp = &xs[oh * 20 + ow];
    float acc = cb
       + xp[0] * w[0] + xp[1] * w[1] + xp[2] * w[2]
       + xp[20] * w[3] + xp[21] * w[4] + xp[22] * w[5]
       + xp[40] * w[6] + xp[41] * w[7] + xp[42] * w[8];
    yb[(long)b * FCIN + c * HW + e] = f32_to_bf16(acc);
    s += acc; sq += acc * acc;
  }
  s += __shfl_xor(s, 1, 64); sq += __shfl_xor(sq, 1, 64);
  s += __shfl_xor(s, 2, 64); sq += __shfl_xor(sq, 2, 64);
  s += __shfl_xor(s, 4, 64); sq += __shfl_xor(sq, 4, 64);
  if (sub == 0) { ssum[c] = s; ssq[c] = sq; }
  __syncthreads();
  if (t < 32) {
    atomicAdd(&dacc[2 + t], (double)ssum[t]);
    atomicAdd(&dacc[34 + t], (double)ssq[t]);
  }
}

// K3: in-place bn1 + relu on yb (bf16)
__global__ __launch_bounds__(256) void k_prep(unsigned short* __restrict__ yb,
                                              const float* __restrict__ g1,
                                              const float* __restrict__ b1,
                                              const double* __restrict__ dacc) {
  __shared__ float a1s[32], sh1s[32];
  int t = threadIdx.x;
  if (t < 32) {
    double cnt = 512.0 * 324.0;
    double m = dacc[2 + t] / cnt, v = dacc[34 + t] / cnt - m * m;
    float a = g1[t] * rsqrtf((float)v + BNEPS);
    a1s[t] = a; sh1s[t] = b1[t] - (float)m * a;
  }
  __syncthreads();
  int g = blockIdx.x * 256 + t;          // 0..663551 (x8 elems)
  int row = g / 1296;
  int c8 = (g - row * 1296) * 8;
  unsigned short* p = yb + (long)row * FCIN + c8;
  ushort4 v0 = ((ushort4*)p)[0], v1 = ((ushort4*)p)[1];
  unsigned short e[8] = {v0.x, v0.y, v0.z, v0.w, v1.x, v1.y, v1.z, v1.w};
#pragma unroll
  for (int j = 0; j < 8; j++) {
    int c = (c8 + j) / HW;
    float f = a1s[c] * bf16_to_f32(e[j]) + sh1s[c];
    e[j] = f32_to_bf16(fmaxf(f, 0.f));
  }
  v0.x = e[0]; v0.y = e[1]; v0.z = e[2]; v0.w = e[3];
  v1.x = e[4]; v1.y = e[5]; v1.z = e[6]; v1.w = e[7];
  ((ushort4*)p)[0] = v0; ((ushort4*)p)[1] = v1;
}

// K4: FC GEMM via bf16 MFMA. 384 single-wave blocks = 12 kslices x (8 mt x 4 nt).
__global__ __launch_bounds__(64) void k_fc3(const unsigned short* __restrict__ yb,
                                            const unsigned short* __restrict__ fcwb,
                                            float* __restrict__ Cp) {
  int wid = blockIdx.x;             // 384 = 12 ks * 32 tiles
  int ks = wid >> 5, rem = wid & 31;
  int mt = rem >> 2, nt = rem & 3;
  int m0 = mt * 64, n0 = nt * 64;
  int lane = threadIdx.x;
  int quad = lane >> 4, lr = lane & 15;
  long kbeg = (long)ks * 864;       // 27 chunks of 32

  const unsigned short* arow[4];
  const unsigned short* brow[4];
#pragma unroll
  for (int mi = 0; mi < 4; mi++)
    arow[mi] = yb + (long)(m0 + mi * 16 + lr) * FCIN + kbeg + quad * 8;
#pragma unroll
  for (int ni = 0; ni < 4; ni++) {
    int d = n0 + ni * 16 + lr;
    if (d > DD - 1) d = DD - 1;
    brow[ni] = fcwb + (long)d * FCIN + kbeg + quad * 8;
  }

  floatx4 acc[4][4];
#pragma unroll
  for (int i = 0; i < 4; i++)
#pragma unroll
    for (int j = 0; j < 4; j++) acc[i][j] = (floatx4){0.f, 0.f, 0.f, 0.f};

  short8 sA[3][4], sB[3][4];
#pragma unroll
  for (int c = 0; c < 3; c++) {
#pragma unroll
    for (int mi = 0; mi < 4; mi++) sA[c][mi] = *(const short8*)(arow[mi] + c * 32);
#pragma unroll
    for (int ni = 0; ni < 4; ni++) sB[c][ni] = *(const short8*)(brow[ni] + c * 32);
  }
  for (int c3 = 0; c3 < 9; c3++) {
    int cc = c3 * 3;
#pragma unroll
    for (int j = 0; j < 3; j++) {
#pragma unroll
      for (int ni = 0; ni < 4; ni++)
#pragma unroll
        for (int mi = 0; mi < 4; mi++)
          acc[mi][ni] = __builtin_amdgcn_mfma_f32_16x16x32_bf16(sA[j][mi], sB[j][ni], acc[mi][ni], 0, 0, 0);
      int nxt = cc + j + 3;
      if (nxt < 27) {
#pragma unroll
        for (int mi = 0; mi < 4; mi++) sA[j][mi] = *(const short8*)(arow[mi] + nxt * 32);
#pragma unroll
        for (int ni = 0; ni < 4; ni++) sB[j][ni] = *(const short8*)(brow[ni] + nxt * 32);
      }
    }
  }

  float* out = Cp + (long)ks * (NB_B * DD);
#pragma unroll
  for (int ni = 0; ni < 4; ni++) {
    int d = n0 + ni * 16 + lr;
    if (d < DD) {
#pragma unroll
      for (int mi = 0; mi < 4; mi++) {
        int mbase = m0 + mi * 16 + quad * 4;
#pragma unroll
        for (int rg = 0; rg < 4; rg++)
          out[(mbase + rg) * DD + d] = acc[mi][ni][rg];
      }
    }
  }
}

// K4b (fused): reduce 12 partials -> Cfc AND bn2 stats -> a2/b2c.
__global__ void k_fcbn(const float* __restrict__ Cp, const float* __restrict__ fcb,
                       const float* __restrict__ g2, const float* __restrict__ b2,
                       float* __restrict__ Cfc, float* __restrict__ a2,
                       float* __restrict__ b2c) {
  int d = blockIdx.x, lane = threadIdx.x;
  float fb = fcb[d];
  float s = 0.f, sq = 0.f;
  for (int b = lane; b < NB_B; b += 64) {
    float v = 0.f;
#pragma unroll
    for (int p = 0; p < 12; p++) v += Cp[(long)p * (NB_B * DD) + b * DD + d];
    Cfc[b * DD + d] = v;
    float w = v + fb;
    s += w; sq += w * w;
  }
  for (int o = 32; o > 0; o >>= 1) { s += __shfl_down(s, o, 64); sq += __shfl_down(sq, o, 64); }
  if (lane == 0) {
    float m = s / 512.f, v = sq / 512.f - m * m;
    float a = g2[d] * rsqrtf(v + BNEPS);
    a2[d] = a; b2c[d] = b2[d] - m * a;
  }
}

// K6: x_final row: leaky_relu(bn2(fc)) -> xf f32 + xfb bf16(padded); fused pos-score
__global__ __launch_bounds__(256) void k_xfinal(const float* __restrict__ Cfc,
                         const float* __restrict__ fcb,
                         const float* __restrict__ a2, const float* __restrict__ b2c,
                         const float* __restrict__ ent, const float* __restrict__ bias,
                         const int* __restrict__ pos,
                         float* __restrict__ xf, unsigned short* __restrict__ xfb,
                         double* dacc) {
  __shared__ float xs[224];
  __shared__ float sbuf[8];
  int b = blockIdx.x, t = threadIdx.x;
  if (t < KP) {
    float xv = 0.f;
    if (t < DD) {
      float v = Cfc[b * DD + t] + fcb[t];
      xv = a2[t] * v + b2c[t];
      xv = xv >= 0.f ? xv : 0.01f * xv;
      xf[b * DD + t] = xv;
    }
    xfb[b * KP + t] = f32_to_bf16(xv);
    xs[t] = xv;
  }
  __syncthreads();
  int e = pos[b];
  float s = (t < DD) ? xs[t] * ent[(long)e * DD + t] : 0.f;
  float ts = blk_reduce(s, sbuf);
  if (t == 0) atomicAdd(&dacc[70], (double)(ts + bias[e]));
}

// ---------------------------------------------------------------------------
// K7: scores GEMM + fused softplus. Round-15 = R14 deep pipeline with both
// regressions removed:
//  (a) entb is TILED CHUNK-MAJOR -> gload_lds writes stay linear AND
//      ds_read_b128 at c*512 + rr*16 is the proven conflict-free pattern
//      (R12: 100K conflicts vs R13/R14 row-major: 2.8M).
//  (b) bias preload bv[7][2] (spill source, WRITE 161MB) replaced by a
//      rotating 2-reg prefetch (bv/bvn). Live set ~90 VGPR < 128.
// Grid 1024 = 4 blocks/CU exactly; 512 chunks x 2 row-halves; 6-7 tiles each;
// stage(i+1) issued before compute(i); one barrier per tile.
// ---------------------------------------------------------------------------
static __device__ __forceinline__ void sc_compute10(
    const unsigned short* __restrict__ buf, const float (&bv)[2],
    const short8 (&af)[2][7], int quad, int lr, float& sp, float& ss) {
#pragma unroll
  for (int ni = 0; ni < 2; ni++) {
    float b1v = bv[ni];
    floatx4 acc0 = (floatx4){0.f, 0.f, 0.f, 0.f};
    floatx4 acc1 = (floatx4){0.f, 0.f, 0.f, 0.f};
#pragma unroll
    for (int kc = 0; kc < 7; kc++) {
      int c = kc * 4 + quad;
      short8 bsv = *(const short8*)(buf + c * 256 + (ni * 16 + lr) * 8);
      acc0 = __builtin_amdgcn_mfma_f32_16x16x32_bf16(af[0][kc], bsv, acc0, 0, 0, 0);
      acc1 = __builtin_amdgcn_mfma_f32_16x16x32_bf16(af[1][kc], bsv, acc1, 0, 0, 0);
    }
    // softplus in log2 domain: softplus(s) = ln2*(max(m1,0)+log2(1+2^-|m1|))
#pragma unroll
    for (int rg2 = 0; rg2 < 4; rg2++) {
      float s1 = acc0[rg2] + b1v;
      ss += s1;
      float m1 = s1 * 1.4426950408889634f;
      float e2 = __builtin_amdgcn_exp2f(-__builtin_fabsf(m1));
      sp += fmaxf(m1, 0.f) + __builtin_amdgcn_logf(1.f + e2);
    }
#pragma unroll
    for (int rg2 = 0; rg2 < 4; rg2++) {
      float s1 = acc1[rg2] + b1v;
      ss += s1;
      float m1 = s1 * 1.4426950408889634f;
      float e2 = __builtin_amdgcn_exp2f(-__builtin_fabsf(m1));
      sp += fmaxf(m1, 0.f) + __builtin_amdgcn_logf(1.f + e2);
    }
  }
}

__global__ __launch_bounds__(512) void k_scores10(
    const unsigned short* __restrict__ entb,  // tiled chunk-major bf16
    const unsigned short* __restrict__ xfb,   // [512][KP] bf16 bits
    const float* __restrict__ bias, double* dacc) {
  __shared__ unsigned short Bs[2][7168];      // 2 x 14 KB (one 32-ent tile)
  __shared__ float sbuf[8];
  int t = threadIdx.x;
  int wv = t >> 6, lane = t & 63;
  int quad = lane >> 4, lr = lane & 15;
  int b = blockIdx.x;
  int rh = b & 1;                  // row half: rows [rh*256, rh*256+256)
  int chunk = b >> 1;              // 512 chunks over 3126 tiles (32 ents each)
  int nt = (chunk < 54) ? 7 : 6;   // 54*7 + 458*6 = 3126
  int t0 = chunk * 6 + (chunk < 54 ? chunk : 54);

  short8 af[2][7];
#pragma unroll
  for (int mi = 0; mi < 2; mi++) {
    const unsigned short* ap =
        xfb + (size_t)(rh * 256 + wv * 32 + mi * 16 + lr) * KP + quad * 8;
#pragma unroll
    for (int kc = 0; kc < 7; kc++) af[mi][kc] = *(const short8*)(ap + kc * 32);
  }

  // async stage: wave wv issues slots {wv*2, wv*2+1} (<14); 1 KB per call.
  // entb tile base = tile*7168 shorts; slot s_ covers shorts [s_*512, +512).
#define STAGE10(bufi, tile)                                                    \
  {                                                                            \
    _Pragma("unroll")                                                          \
    for (int i_ = 0; i_ < 2; i_++) {                                           \
      int s_ = wv * 2 + i_;                                                    \
      if (s_ < 14) {                                                           \
        const unsigned short* gp_ =                                            \
            entb + (size_t)(tile) * 7168 + s_ * 512 + lane * 8;                \
        __builtin_amdgcn_global_load_lds(                                      \
            (const __attribute__((address_space(1))) unsigned int*)gp_,       \
            (__attribute__((address_space(3))) unsigned int*)&Bs[bufi][s_ * 512], \
            16, 0, 0);                                                         \
      }                                                                        \
    }                                                                          \
  }

  float sp = 0.f, ss = 0.f;
  float bv[2], bvn[2];

  STAGE10(0, t0);
#pragma unroll
  for (int ni = 0; ni < 2; ni++) {
    int e = t0 * 32 + ni * 16 + lr;
    bv[ni] = (e < NE) ? bias[e] : 0.f;
  }
  __syncthreads();                      // drain first stage
#pragma unroll
  for (int i = 0; i < 7; i++) {
    if (i < nt) {
      if (i + 1 < nt) {
        STAGE10((i + 1) & 1, t0 + i + 1);   // overlaps compute(i)
#pragma unroll
        for (int ni = 0; ni < 2; ni++) {
          int e = (t0 + i + 1) * 32 + ni * 16 + lr;
          bvn[ni] = (e < NE) ? bias[e] : 0.f;
        }
      }
      sc_compute10(Bs[i & 1], bv, af, quad, lr, sp, ss);
      __syncthreads();                  // drains stage(i+1); frees Bs[i&1]
      bv[0] = bvn[0]; bv[1] = bvn[1];
    }
  }
#undef STAGE10

  sp *= 0.6931471805599453f;  // ln2
  float tsp = blk_reduce(sp, sbuf);
  float tss = blk_reduce(ss, sbuf);
  if (t == 0) {
    atomicAdd(&dacc[68], (double)tsp);
    atomicAdd(&dacc[69], (double)tss);
  }
}

// K8: final scalar (64 threads; also does conv_w L2 reduce).
// Subtract pad softplus constant: 512 rows x 32 pad entities x ln2
// (tile 3125 = pad rows, computed by both row-halves of chunk 511).
__global__ void k_final(const float* __restrict__ convw, const double* dacc, float* out) {
  int t = threadIdx.x;
  float sq = 0.f;
  for (int i = t; i < 288; i += 64) { float w = convw[i]; sq += w * w; }
  for (int o = 32; o > 0; o >>= 1) sq += __shfl_down(sq, o, 64);
  if (t == 0) {
    double SP = dacc[68] - 16384.0 * 0.6931471805599453;
    double S2 = dacc[69], S3 = dacc[70];
    double xy = S2 / (double)NE + 0.9 * S3;
    double kg = (SP - xy) / ((double)NB_B * (double)NE);
    double l2 = dacc[1] / 204800.0 + (double)sq / 576.0 + dacc[67] / 400.0;
    out[0] = (float)(kg + 1e-5 * l2);
  }
}

extern "C" void kernel_launch(void* const* d_in, const int* in_sizes, int n_in,
                              void* d_out, int out_size, void* d_ws, size_t ws_size,
                              hipStream_t stream) {
  const float* ent   = (const float*)d_in[0];
  const float* rel   = (const float*)d_in[1];
  const float* convw = (const float*)d_in[2];
  const float* convb = (const float*)d_in[3];
  const float* fcw   = (const float*)d_in[4];
  const float* fcb   = (const float*)d_in[5];
  const float* bias  = (const float*)d_in[6];
  const float* g0    = (const float*)d_in[7];
  const float* b0    = (const float*)d_in[8];
  const float* g1    = (const float*)d_in[9];
  const float* b1    = (const float*)d_in[10];
  const float* g2    = (const float*)d_in[11];
  const float* b2    = (const float*)d_in[12];
  const int*   h     = (const int*)d_in[13];
  const int*   r     = (const int*)d_in[14];
  const int*   pos   = (const int*)d_in[15];

  char* ws = (char*)d_ws;
  double* dacc = (double*)(ws + 0);                        // 8 KB
  float* a2  = (float*)(ws + 16384 + 256);                 // 200
  float* b2c = (float*)(ws + 16384 + 1056);                // 200
  float* x0  = (float*)(ws + 32768);                       // 512*400 f32      (819200 B)
  float* Cfc = (float*)(ws + 851968);                      // 512*200 f32      (409600 B)
  float* xf  = (float*)(ws + 1261568);                     // 512*200 f32      (409600 B)
  unsigned short* yb   = (unsigned short*)(ws + 1671168);  // 512*10368 bf16   (10616832 B)
  unsigned short* fcwb = (unsigned short*)(ws + 12288000); // 200*10368 bf16   (4147200 B)
  unsigned short* xfb  = (unsigned short*)(ws + 16435200); // 512*224 bf16     (229376 B)
  unsigned short* entb = (unsigned short*)(ws + 16664576); // 3126 tiles x 14336 B (44814336 B)
  float* Cp = (float*)(ws + 61507584);                     // 12*512*200 f32   (4915200 B) -> 66.4MB

  hipMemsetAsync(dacc, 0, 8192, stream);

  k_cvt<<<GATH_OFF + 512, 256, 0, stream>>>(ent, entb, fcw, fcwb, rel, h, r, x0, dacc);
  k_conv<<<512, 256, 0, stream>>>(x0, convw, convb, g0, b0, yb, dacc);
  k_prep<<<2592, 256, 0, stream>>>(yb, g1, b1, dacc);
  k_fc3<<<384, 64, 0, stream>>>(yb, fcwb, Cp);
  k_fcbn<<<200, 64, 0, stream>>>(Cp, fcb, g2, b2, Cfc, a2, b2c);
  k_xfinal<<<512, 256, 0, stream>>>(Cfc, fcb, a2, b2c, ent, bias, pos, xf, xfb, dacc);
  k_scores10<<<1024, 512, 0, stream>>>(entb, xfb, bias, dacc);
  k_final<<<1, 64, 0, stream>>>(convw, dacc, (float*)d_out);
}

// Round 16
// 296.513 us; speedup vs baseline: 1.5610x; 1.5610x over previous
//
#include <hip/hip_runtime.h>
#include <math.h>

#define NB_B 512
#define NE 100000
#define NE_PAD 100032   // 3126 tiles x 32 rows (pad rows 100000..100031 zero)
#define DD 200
#define CC 32
#define FCIN 10368   // 32*18*18
#define HW 324       // 18*18
#define BNEPS 1e-5f
#define KP 224       // scores K padded to multiple of 32 for MFMA

#define ENT_BLKS 10941   // 100032*28/256 exactly
#define FCW_BLKS 1013
#define GATH_OFF (ENT_BLKS + FCW_BLKS)   // 11954

typedef __attribute__((ext_vector_type(8))) short short8;   // 8 bf16 = 4 VGPRs
typedef __attribute__((ext_vector_type(4))) float floatx4;  // MFMA acc

// dacc (double) slots:
// 0: bn0 sum, 1: bn0 sumsq (also l2 for h_e+r_e)
// 2..33: bn1 per-channel sum, 34..65: bn1 per-channel sumsq
// 67: fc_w sumsq, 68: softplus sum (incl. pad constant), 69: scores sum, 70: pos-scores sum

static __device__ __forceinline__ float blk_reduce(float v, volatile float* sbuf) {
  for (int o = 32; o > 0; o >>= 1) v += __shfl_down(v, o, 64);
  int lane = threadIdx.x & 63, wid = threadIdx.x >> 6;
  if (lane == 0) sbuf[wid] = v;
  __syncthreads();
  float r = 0.f;
  int nw = (blockDim.x + 63) >> 6;
  if ((int)threadIdx.x < nw) r = sbuf[threadIdx.x];
  if (threadIdx.x < 64) {
    for (int o = 32; o > 0; o >>= 1) r += __shfl_down(r, o, 64);
  }
  __syncthreads();
  return r;  // valid on thread 0
}

static __device__ __forceinline__ unsigned short f32_to_bf16(float f) {
  unsigned int u = __float_as_uint(f);
  u += 0x7fffu + ((u >> 16) & 1u);  // round-to-nearest-even
  return (unsigned short)(u >> 16);
}
static __device__ __forceinline__ float bf16_to_f32(unsigned short b) {
  return __uint_as_float(((unsigned int)b) << 16);
}

// K1: fused prep (3-branch). Blocks [0,ENT_BLKS): entity f32->bf16 into entb in
// TILED CHUNK-MAJOR layout: tile=row/32, rr=row%32, chunk c; short offset
// = tile*7168 + c*256 + rr*8. gload_lds writes linear; ds_read conflict-free
// (verified R15: SQ_LDS_BANK_CONFLICT = 0).
// [ENT_BLKS,GATH_OFF): fc_w -> bf16 + sumsq. [GATH_OFF,+512): gather, bn0.
__global__ __launch_bounds__(256) void k_cvt(const float* __restrict__ ent,
                                             unsigned short* __restrict__ entb,
                                             const float* __restrict__ fcw,
                                             unsigned short* __restrict__ fcwb,
                                             const float* __restrict__ rel,
                                             const int* __restrict__ h,
                                             const int* __restrict__ r,
                                             float* __restrict__ x0,
                                             double* dacc) {
  if (blockIdx.x < ENT_BLKS) {
    int g = blockIdx.x * 256 + threadIdx.x;   // 0 .. 2,800,895  (100032*28)
    int row = g / 28;
    int c = g - row * 28;                     // chunk 0..27
    int c8 = c * 8;
    short8 o;
    if (c8 < 200 && row < NE) {
      const float4* s = (const float4*)(ent + (long)row * DD + c8);
      float4 u = s[0], v = s[1];
      o[0] = (short)f32_to_bf16(u.x); o[1] = (short)f32_to_bf16(u.y);
      o[2] = (short)f32_to_bf16(u.z); o[3] = (short)f32_to_bf16(u.w);
      o[4] = (short)f32_to_bf16(v.x); o[5] = (short)f32_to_bf16(v.y);
      o[6] = (short)f32_to_bf16(v.z); o[7] = (short)f32_to_bf16(v.w);
    } else {
      o = (short8){0, 0, 0, 0, 0, 0, 0, 0};
    }
    int tile = row >> 5, rr = row & 31;
    *(short8*)(entb + (long)tile * 7168 + c * 256 + rr * 8) = o;
  } else if (blockIdx.x < GATH_OFF) {
    int g = (blockIdx.x - ENT_BLKS) * 256 + threadIdx.x;   // x8 elems
    float sq = 0.f;
    if (g < 259200) {
      const float4* s = (const float4*)(fcw + (long)g * 8);
      float4 u = s[0], v = s[1];
      sq = u.x*u.x + u.y*u.y + u.z*u.z + u.w*u.w
         + v.x*v.x + v.y*v.y + v.z*v.z + v.w*v.w;
      ushort4 o0, o1;
      o0.x = f32_to_bf16(u.x); o0.y = f32_to_bf16(u.y);
      o0.z = f32_to_bf16(u.z); o0.w = f32_to_bf16(u.w);
      o1.x = f32_to_bf16(v.x); o1.y = f32_to_bf16(v.y);
      o1.z = f32_to_bf16(v.z); o1.w = f32_to_bf16(v.w);
      ushort4* d = (ushort4*)(fcwb + (long)g * 8);
      d[0] = o0; d[1] = o1;
    }
    __shared__ float sbuf[8];
    float tq = blk_reduce(sq, sbuf);
    if (threadIdx.x == 0) atomicAdd(&dacc[67], (double)tq);
  } else {
    int b = blockIdx.x - GATH_OFF;
    int hi = h[b], ri = r[b];
    float s = 0.f, sq = 0.f;
    for (int i = threadIdx.x; i < 400; i += 256) {
      float v = (i < 200) ? ent[(long)hi * DD + i] : rel[(long)ri * DD + (i - 200)];
      x0[b * 400 + i] = v;
      s += v; sq += v * v;
    }
    __shared__ float sbuf[8];
    float ts = blk_reduce(s, sbuf);
    float tq = blk_reduce(sq, sbuf);
    if (threadIdx.x == 0) {
      atomicAdd(&dacc[0], (double)ts);
      atomicAdd(&dacc[1], (double)tq);
    }
  }
}

// K2: bn0 + conv3x3 + conv_b -> yb bf16 [512 x 10368] (pre-bn1); bn1 stats (f32)
__global__ __launch_bounds__(256) void k_conv(const float* __restrict__ x0,
                       const float* __restrict__ convw, const float* __restrict__ convb,
                       const float* __restrict__ g0, const float* __restrict__ b0,
                       unsigned short* __restrict__ yb, double* dacc) {
  __shared__ float xs[400], wsm[288], cbs[32], ssum[32], ssq[32];
  __shared__ float a0s, s0s;
  int b = blockIdx.x, t = threadIdx.x;
  for (int i = t; i < 400; i += 256) xs[i] = x0[b * 400 + i];
  for (int i = t; i < 288; i += 256) wsm[i] = convw[i];
  if (t < 32) cbs[t] = convb[t];
  if (t == 0) {
    double m = dacc[0] / 204800.0;
    double v = dacc[1] / 204800.0 - m * m;
    float a = g0[0] * rsqrtf((float)v + BNEPS);
    a0s = a; s0s = b0[0] - (float)m * a;
  }
  __syncthreads();
  float a0 = a0s, s0 = s0s;
  for (int i = t; i < 400; i += 256) xs[i] = a0 * xs[i] + s0;
  __syncthreads();
  int c = t >> 3, sub = t & 7;
  const float* w = &wsm[c * 9];
  float cb = cbs[c];
  float s = 0.f, sq = 0.f;
  for (int e = sub; e < HW; e += 8) {
    int oh = e / 18, ow = e - oh * 18;
    const float* xp = &xs[oh * 20 + ow];
    float acc = cb
       + xp[0] * w[0] + xp[1] * w[1] + xp[2] * w[2]
       + xp[20] * w[3] + xp[21] * w[4] + xp[22] * w[5]
       + xp[40] * w[6] + xp[41] * w[7] + xp[42] * w[8];
    yb[(long)b * FCIN + c * HW + e] = f32_to_bf16(acc);
    s += acc; sq += acc * acc;
  }
  s += __shfl_xor(s, 1, 64); sq += __shfl_xor(sq, 1, 64);
  s += __shfl_xor(s, 2, 64); sq += __shfl_xor(sq, 2, 64);
  s += __shfl_xor(s, 4, 64); sq += __shfl_xor(sq, 4, 64);
  if (sub == 0) { ssum[c] = s; ssq[c] = sq; }
  __syncthreads();
  if (t < 32) {
    atomicAdd(&dacc[2 + t], (double)ssum[t]);
    atomicAdd(&dacc[34 + t], (double)ssq[t]);
  }
}

// K3: in-place bn1 + relu on yb (bf16)
__global__ __launch_bounds__(256) void k_prep(unsigned short* __restrict__ yb,
                                              const float* __restrict__ g1,
                                              const float* __restrict__ b1,
                                              const double* __restrict__ dacc) {
  __shared__ float a1s[32], sh1s[32];
  int t = threadIdx.x;
  if (t < 32) {
    double cnt = 512.0 * 324.0;
    double m = dacc[2 + t] / cnt, v = dacc[34 + t] / cnt - m * m;
    float a = g1[t] * rsqrtf((float)v + BNEPS);
    a1s[t] = a; sh1s[t] = b1[t] - (float)m * a;
  }
  __syncthreads();
  int g = blockIdx.x * 256 + t;          // 0..663551 (x8 elems)
  int row = g / 1296;
  int c8 = (g - row * 1296) * 8;
  unsigned short* p = yb + (long)row * FCIN + c8;
  ushort4 v0 = ((ushort4*)p)[0], v1 = ((ushort4*)p)[1];
  unsigned short e[8] = {v0.x, v0.y, v0.z, v0.w, v1.x, v1.y, v1.z, v1.w};
#pragma unroll
  for (int j = 0; j < 8; j++) {
    int c = (c8 + j) / HW;
    float f = a1s[c] * bf16_to_f32(e[j]) + sh1s[c];
    e[j] = f32_to_bf16(fmaxf(f, 0.f));
  }
  v0.x = e[0]; v0.y = e[1]; v0.z = e[2]; v0.w = e[3];
  v1.x = e[4]; v1.y = e[5]; v1.z = e[6]; v1.w = e[7];
  ((ushort4*)p)[0] = v0; ((ushort4*)p)[1] = v1;
}

// K4: FC GEMM via bf16 MFMA. 384 single-wave blocks = 12 kslices x (8 mt x 4 nt).
__global__ __launch_bounds__(64) void k_fc3(const unsigned short* __restrict__ yb,
                                            const unsigned short* __restrict__ fcwb,
                                            float* __restrict__ Cp) {
  int wid = blockIdx.x;             // 384 = 12 ks * 32 tiles
  int ks = wid >> 5, rem = wid & 31;
  int mt = rem >> 2, nt = rem & 3;
  int m0 = mt * 64, n0 = nt * 64;
  int lane = threadIdx.x;
  int quad = lane >> 4, lr = lane & 15;
  long kbeg = (long)ks * 864;       // 27 chunks of 32

  const unsigned short* arow[4];
  const unsigned short* brow[4];
#pragma unroll
  for (int mi = 0; mi < 4; mi++)
    arow[mi] = yb + (long)(m0 + mi * 16 + lr) * FCIN + kbeg + quad * 8;
#pragma unroll
  for (int ni = 0; ni < 4; ni++) {
    int d = n0 + ni * 16 + lr;
    if (d > DD - 1) d = DD - 1;
    brow[ni] = fcwb + (long)d * FCIN + kbeg + quad * 8;
  }

  floatx4 acc[4][4];
#pragma unroll
  for (int i = 0; i < 4; i++)
#pragma unroll
    for (int j = 0; j < 4; j++) acc[i][j] = (floatx4){0.f, 0.f, 0.f, 0.f};

  short8 sA[3][4], sB[3][4];
#pragma unroll
  for (int c = 0; c < 3; c++) {
#pragma unroll
    for (int mi = 0; mi < 4; mi++) sA[c][mi] = *(const short8*)(arow[mi] + c * 32);
#pragma unroll
    for (int ni = 0; ni < 4; ni++) sB[c][ni] = *(const short8*)(brow[ni] + c * 32);
  }
  for (int c3 = 0; c3 < 9; c3++) {
    int cc = c3 * 3;
#pragma unroll
    for (int j = 0; j < 3; j++) {
#pragma unroll
      for (int ni = 0; ni < 4; ni++)
#pragma unroll
        for (int mi = 0; mi < 4; mi++)
          acc[mi][ni] = __builtin_amdgcn_mfma_f32_16x16x32_bf16(sA[j][mi], sB[j][ni], acc[mi][ni], 0, 0, 0);
      int nxt = cc + j + 3;
      if (nxt < 27) {
#pragma unroll
        for (int mi = 0; mi < 4; mi++) sA[j][mi] = *(const short8*)(arow[mi] + nxt * 32);
#pragma unroll
        for (int ni = 0; ni < 4; ni++) sB[j][ni] = *(const short8*)(brow[ni] + nxt * 32);
      }
    }
  }

  float* out = Cp + (long)ks * (NB_B * DD);
#pragma unroll
  for (int ni = 0; ni < 4; ni++) {
    int d = n0 + ni * 16 + lr;
    if (d < DD) {
#pragma unroll
      for (int mi = 0; mi < 4; mi++) {
        int mbase = m0 + mi * 16 + quad * 4;
#pragma unroll
        for (int rg = 0; rg < 4; rg++)
          out[(mbase + rg) * DD + d] = acc[mi][ni][rg];
      }
    }
  }
}

// K4b (fused): reduce 12 partials -> Cfc AND bn2 stats -> a2/b2c.
__global__ void k_fcbn(const float* __restrict__ Cp, const float* __restrict__ fcb,
                       const float* __restrict__ g2, const float* __restrict__ b2,
                       float* __restrict__ Cfc, float* __restrict__ a2,
                       float* __restrict__ b2c) {
  int d = blockIdx.x, lane = threadIdx.x;
  float fb = fcb[d];
  float s = 0.f, sq = 0.f;
  for (int b = lane; b < NB_B; b += 64) {
    float v = 0.f;
#pragma unroll
    for (int p = 0; p < 12; p++) v += Cp[(long)p * (NB_B * DD) + b * DD + d];
    Cfc[b * DD + d] = v;
    float w = v + fb;
    s += w; sq += w * w;
  }
  for (int o = 32; o > 0; o >>= 1) { s += __shfl_down(s, o, 64); sq += __shfl_down(sq, o, 64); }
  if (lane == 0) {
    float m = s / 512.f, v = sq / 512.f - m * m;
    float a = g2[d] * rsqrtf(v + BNEPS);
    a2[d] = a; b2c[d] = b2[d] - m * a;
  }
}

// K6: x_final row: leaky_relu(bn2(fc)) -> xf f32 + xfb bf16(padded); fused pos-score
__global__ __launch_bounds__(256) void k_xfinal(const float* __restrict__ Cfc,
                         const float* __restrict__ fcb,
                         const float* __restrict__ a2, const float* __restrict__ b2c,
                         const float* __restrict__ ent, const float* __restrict__ bias,
                         const int* __restrict__ pos,
                         float* __restrict__ xf, unsigned short* __restrict__ xfb,
                         double* dacc) {
  __shared__ float xs[224];
  __shared__ float sbuf[8];
  int b = blockIdx.x, t = threadIdx.x;
  if (t < KP) {
    float xv = 0.f;
    if (t < DD) {
      float v = Cfc[b * DD + t] + fcb[t];
      xv = a2[t] * v + b2c[t];
      xv = xv >= 0.f ? xv : 0.01f * xv;
      xf[b * DD + t] = xv;
    }
    xfb[b * KP + t] = f32_to_bf16(xv);
    xs[t] = xv;
  }
  __syncthreads();
  int e = pos[b];
  float s = (t < DD) ? xs[t] * ent[(long)e * DD + t] : 0.f;
  float ts = blk_reduce(s, sbuf);
  if (t == 0) atomicAdd(&dacc[70], (double)(ts + bias[e]));
}

// ---------------------------------------------------------------------------
// K7: scores GEMM + fused softplus. Round-16 = R15 with the spill source
// removed: the tile loop is a RUNTIME loop (#pragma unroll 1) with runtime
// ping-pong LDS index `cur` (legal: runtime LDS *address*, not a register
// array index). R14/R15's full 7x unroll let the compiler hoist all
// iterations' prefetch state -> 128-VGPR cap + 344MB scratch. Runtime loop
// live set: af 56 + bv/bvn 4 + ptrs ~10 + compute temps ~25 = ~95 VGPR.
// Chunk-major entb kept (R15 verified: bank conflicts = 0).
// Grid 1024 = 4 blocks/CU; 512 chunks x 2 row-halves; 6-7 tiles each;
// stage(i+1) issued before compute(i); one barrier per tile.
// ---------------------------------------------------------------------------
static __device__ __forceinline__ void sc_compute10(
    const unsigned short* __restrict__ buf, const float (&bv)[2],
    const short8 (&af)[2][7], int quad, int lr, float& sp, float& ss) {
#pragma unroll
  for (int ni = 0; ni < 2; ni++) {
    float b1v = bv[ni];
    floatx4 acc0 = (floatx4){0.f, 0.f, 0.f, 0.f};
    floatx4 acc1 = (floatx4){0.f, 0.f, 0.f, 0.f};
#pragma unroll
    for (int kc = 0; kc < 7; kc++) {
      int c = kc * 4 + quad;
      short8 bsv = *(const short8*)(buf + c * 256 + (ni * 16 + lr) * 8);
      acc0 = __builtin_amdgcn_mfma_f32_16x16x32_bf16(af[0][kc], bsv, acc0, 0, 0, 0);
      acc1 = __builtin_amdgcn_mfma_f32_16x16x32_bf16(af[1][kc], bsv, acc1, 0, 0, 0);
    }
    // softplus in log2 domain: softplus(s) = ln2*(max(m1,0)+log2(1+2^-|m1|))
#pragma unroll
    for (int rg2 = 0; rg2 < 4; rg2++) {
      float s1 = acc0[rg2] + b1v;
      ss += s1;
      float m1 = s1 * 1.4426950408889634f;
      float e2 = __builtin_amdgcn_exp2f(-__builtin_fabsf(m1));
      sp += fmaxf(m1, 0.f) + __builtin_amdgcn_logf(1.f + e2);
    }
#pragma unroll
    for (int rg2 = 0; rg2 < 4; rg2++) {
      float s1 = acc1[rg2] + b1v;
      ss += s1;
      float m1 = s1 * 1.4426950408889634f;
      float e2 = __builtin_amdgcn_exp2f(-__builtin_fabsf(m1));
      sp += fmaxf(m1, 0.f) + __builtin_amdgcn_logf(1.f + e2);
    }
  }
}

__global__ __launch_bounds__(512) void k_scores11(
    const unsigned short* __restrict__ entb,  // tiled chunk-major bf16
    const unsigned short* __restrict__ xfb,   // [512][KP] bf16 bits
    const float* __restrict__ bias, double* dacc) {
  __shared__ unsigned short Bs[2][7168];      // 2 x 14 KB (one 32-ent tile)
  __shared__ float sbuf[8];
  int t = threadIdx.x;
  int wv = t >> 6, lane = t & 63;
  int quad = lane >> 4, lr = lane & 15;
  int b = blockIdx.x;
  int rh = b & 1;                  // row half: rows [rh*256, rh*256+256)
  int chunk = b >> 1;              // 512 chunks over 3126 tiles (32 ents each)
  int nt = (chunk < 54) ? 7 : 6;   // 54*7 + 458*6 = 3126
  int t0 = chunk * 6 + (chunk < 54 ? chunk : 54);

  short8 af[2][7];
#pragma unroll
  for (int mi = 0; mi < 2; mi++) {
    const unsigned short* ap =
        xfb + (size_t)(rh * 256 + wv * 32 + mi * 16 + lr) * KP + quad * 8;
#pragma unroll
    for (int kc = 0; kc < 7; kc++) af[mi][kc] = *(const short8*)(ap + kc * 32);
  }

  // async stage into runtime-selected buffer (LDS address, not reg array)
#define STAGE11(bufp, tile)                                                    \
  {                                                                            \
    _Pragma("unroll")                                                          \
    for (int i_ = 0; i_ < 2; i_++) {                                           \
      int s_ = wv * 2 + i_;                                                    \
      if (s_ < 14) {                                                           \
        const unsigned short* gp_ =                                            \
            entb + (size_t)(tile) * 7168 + s_ * 512 + lane * 8;                \
        __builtin_amdgcn_global_load_lds(                                      \
            (const __attribute__((address_space(1))) unsigned int*)gp_,       \
            (__attribute__((address_space(3))) unsigned int*)((bufp) + s_ * 512), \
            16, 0, 0);                                                         \
      }                                                                        \
    }                                                                          \
  }

  float sp = 0.f, ss = 0.f;
  float bv[2], bvn[2];

  STAGE11(&Bs[0][0], t0);
#pragma unroll
  for (int ni = 0; ni < 2; ni++) {
    int e = t0 * 32 + ni * 16 + lr;
    bv[ni] = (e < NE) ? bias[e] : 0.f;
  }
  __syncthreads();                      // drain first stage

  int cur = 0;
#pragma unroll 1
  for (int i = 0; i < nt; i++) {
    if (i + 1 < nt) {
      STAGE11(&Bs[cur ^ 1][0], t0 + i + 1);   // overlaps compute(i)
      int e0n = (t0 + i + 1) * 32 + lr;
      bvn[0] = (e0n < NE) ? bias[e0n] : 0.f;
      bvn[1] = (e0n + 16 < NE) ? bias[e0n + 16] : 0.f;
    }
    sc_compute10(&Bs[cur][0], bv, af, quad, lr, sp, ss);
    __syncthreads();                    // drains stage(i+1); frees Bs[cur]
    bv[0] = bvn[0]; bv[1] = bvn[1];
    cur ^= 1;
  }
#undef STAGE11

  sp *= 0.6931471805599453f;  // ln2
  float tsp = blk_reduce(sp, sbuf);
  float tss = blk_reduce(ss, sbuf);
  if (t == 0) {
    atomicAdd(&dacc[68], (double)tsp);
    atomicAdd(&dacc[69], (double)tss);
  }
}

// K8: final scalar (64 threads; also does conv_w L2 reduce).
// Subtract pad softplus constant: 512 rows x 32 pad entities x ln2
// (tile 3125 = pad rows, computed by both row-halves of chunk 511).
__global__ void k_final(const float* __restrict__ convw, const double* dacc, float* out) {
  int t = threadIdx.x;
  float sq = 0.f;
  for (int i = t; i < 288; i += 64) { float w = convw[i]; sq += w * w; }
  for (int o = 32; o > 0; o >>= 1) sq += __shfl_down(sq, o, 64);
  if (t == 0) {
    double SP = dacc[68] - 16384.0 * 0.6931471805599453;
    double S2 = dacc[69], S3 = dacc[70];
    double xy = S2 / (double)NE + 0.9 * S3;
    double kg = (SP - xy) / ((double)NB_B * (double)NE);
    double l2 = dacc[1] / 204800.0 + (double)sq / 576.0 + dacc[67] / 400.0;
    out[0] = (float)(kg + 1e-5 * l2);
  }
}

extern "C" void kernel_launch(void* const* d_in, const int* in_sizes, int n_in,
                              void* d_out, int out_size, void* d_ws, size_t ws_size,
                              hipStream_t stream) {
  const float* ent   = (const float*)d_in[0];
  const float* rel   = (const float*)d_in[1];
  const float* convw = (const float*)d_in[2];
  const float* convb = (const float*)d_in[3];
  const float* fcw   = (const float*)d_in[4];
  const float* fcb   = (const float*)d_in[5];
  const float* bias  = (const float*)d_in[6];
  const float* g0    = (const float*)d_in[7];
  const float* b0    = (const float*)d_in[8];
  const float* g1    = (const float*)d_in[9];
  const float* b1    = (const float*)d_in[10];
  const float* g2    = (const float*)d_in[11];
  const float* b2    = (const float*)d_in[12];
  const int*   h     = (const int*)d_in[13];
  const int*   r     = (const int*)d_in[14];
  const int*   pos   = (const int*)d_in[15];

  char* ws = (char*)d_ws;
  double* dacc = (double*)(ws + 0);                        // 8 KB
  float* a2  = (float*)(ws + 16384 + 256);                 // 200
  float* b2c = (float*)(ws + 16384 + 1056);                // 200
  float* x0  = (float*)(ws + 32768);                       // 512*400 f32      (819200 B)
  float* Cfc = (float*)(ws + 851968);                      // 512*200 f32      (409600 B)
  float* xf  = (float*)(ws + 1261568);                     // 512*200 f32      (409600 B)
  unsigned short* yb   = (unsigned short*)(ws + 1671168);  // 512*10368 bf16   (10616832 B)
  unsigned short* fcwb = (unsigned short*)(ws + 12288000); // 200*10368 bf16   (4147200 B)
  unsigned short* xfb  = (unsigned short*)(ws + 16435200); // 512*224 bf16     (229376 B)
  unsigned short* entb = (unsigned short*)(ws + 16664576); // 3126 tiles x 14336 B (44814336 B)
  float* Cp = (float*)(ws + 61507584);                     // 12*512*200 f32   (4915200 B) -> 66.4MB

  hipMemsetAsync(dacc, 0, 8192, stream);

  k_cvt<<<GATH_OFF + 512, 256, 0, stream>>>(ent, entb, fcw, fcwb, rel, h, r, x0, dacc);
  k_conv<<<512, 256, 0, stream>>>(x0, convw, convb, g0, b0, yb, dacc);
  k_prep<<<2592, 256, 0, stream>>>(yb, g1, b1, dacc);
  k_fc3<<<384, 64, 0, stream>>>(yb, fcwb, Cp);
  k_fcbn<<<200, 64, 0, stream>>>(Cp, fcb, g2, b2, Cfc, a2, b2c);
  k_xfinal<<<512, 256, 0, stream>>>(Cfc, fcb, a2, b2c, ent, bias, pos, xf, xfb, dacc);
  k_scores11<<<1024, 512, 0, stream>>>(entb, xfb, bias, dacc);
  k_final<<<1, 64, 0, stream>>>(convw, dacc, (float*)d_out);
}

// Round 17
// 293.065 us; speedup vs baseline: 1.5793x; 1.0118x over previous
//
#include <hip/hip_runtime.h>
#include <math.h>

#define NB_B 512
#define NE 100000
#define NE_PAD 100032   // 3126 tiles x 32 rows (pad rows 100000..100031 zero)
#define DD 200
#define CC 32
#define FCIN 10368   // 32*18*18
#define HW 324       // 18*18
#define BNEPS 1e-5f
#define KP 224       // scores K padded to multiple of 32 for MFMA

#define ENT2_BLKS 3126   // one block per 32-row entity tile
#define FCW_BLKS 1013
#define GATH_OFF2 (ENT2_BLKS + FCW_BLKS)   // 4139

typedef __attribute__((ext_vector_type(8))) short short8;   // 8 bf16 = 4 VGPRs
typedef __attribute__((ext_vector_type(4))) float floatx4;  // MFMA acc

// dacc (double) slots:
// 0: bn0 sum, 1: bn0 sumsq (also l2 for h_e+r_e)
// 2..33: bn1 per-channel sum, 34..65: bn1 per-channel sumsq
// 67: fc_w sumsq, 68: softplus sum (incl. pad constant), 69: scores sum, 70: pos-scores sum

static __device__ __forceinline__ float blk_reduce(float v, volatile float* sbuf) {
  for (int o = 32; o > 0; o >>= 1) v += __shfl_down(v, o, 64);
  int lane = threadIdx.x & 63, wid = threadIdx.x >> 6;
  if (lane == 0) sbuf[wid] = v;
  __syncthreads();
  float r = 0.f;
  int nw = (blockDim.x + 63) >> 6;
  if ((int)threadIdx.x < nw) r = sbuf[threadIdx.x];
  if (threadIdx.x < 64) {
    for (int o = 32; o > 0; o >>= 1) r += __shfl_down(r, o, 64);
  }
  __syncthreads();
  return r;  // valid on thread 0
}

static __device__ __forceinline__ unsigned short f32_to_bf16(float f) {
  unsigned int u = __float_as_uint(f);
  u += 0x7fffu + ((u >> 16) & 1u);  // round-to-nearest-even
  return (unsigned short)(u >> 16);
}
static __device__ __forceinline__ float bf16_to_f32(unsigned short b) {
  return __uint_as_float(((unsigned int)b) << 16);
}

// K1: fused prep (3-branch).
// Blocks [0,ENT2_BLKS): one block per 32-row entity tile. LDS transpose:
//   read 32x200 f32 row-major COALESCED into LDS (row stride 201 floats;
//   201%32=9 coprime -> conflict-free on both access patterns), then write
//   the tiled chunk-major entb slab with consecutive lanes -> consecutive
//   16B addresses = fully coalesced. (R16's direct scatter wrote 16B at
//   stride 512 -> k_cvt ran at 2 TB/s, ~50us.)
// [ENT2_BLKS,GATH_OFF2): fc_w -> bf16 + sumsq. [GATH_OFF2,+512): gather, bn0.
__global__ __launch_bounds__(256) void k_cvt(const float* __restrict__ ent,
                                             unsigned short* __restrict__ entb,
                                             const float* __restrict__ fcw,
                                             unsigned short* __restrict__ fcwb,
                                             const float* __restrict__ rel,
                                             const int* __restrict__ h,
                                             const int* __restrict__ r,
                                             float* __restrict__ x0,
                                             double* dacc) {
  __shared__ float xs[6432];   // 32 rows x 201 floats = 25728 B
  int t = threadIdx.x;
  if (blockIdx.x < ENT2_BLKS) {
    int tile = blockIdx.x;
    // load 32 rows x 200 f32, coalesced (float4); pad rows -> 0
    for (int g = t; g < 1600; g += 256) {
      int rr = g / 50, c4 = g - rr * 50;
      int row = tile * 32 + rr;
      float4 u = {0.f, 0.f, 0.f, 0.f};
      if (row < NE) u = *(const float4*)(ent + (long)row * DD + c4 * 4);
      float* p = &xs[rr * 201 + c4 * 4];
      p[0] = u.x; p[1] = u.y; p[2] = u.z; p[3] = u.w;
    }
    __syncthreads();
    // write chunk-major slab, coalesced: g -> chunk c=g>>5, row rr=g&31
    unsigned short* dst = entb + (long)tile * 7168;
    for (int g = t; g < 896; g += 256) {
      int c = g >> 5, rr = g & 31;
      short8 o = (short8){0, 0, 0, 0, 0, 0, 0, 0};
      if (c < 25) {
        const float* p = &xs[rr * 201 + c * 8];
        o[0] = (short)f32_to_bf16(p[0]); o[1] = (short)f32_to_bf16(p[1]);
        o[2] = (short)f32_to_bf16(p[2]); o[3] = (short)f32_to_bf16(p[3]);
        o[4] = (short)f32_to_bf16(p[4]); o[5] = (short)f32_to_bf16(p[5]);
        o[6] = (short)f32_to_bf16(p[6]); o[7] = (short)f32_to_bf16(p[7]);
      }
      *(short8*)(dst + g * 8) = o;
    }
  } else if (blockIdx.x < GATH_OFF2) {
    int g = (blockIdx.x - ENT2_BLKS) * 256 + t;   // x8 elems
    float sq = 0.f;
    if (g < 259200) {
      const float4* s = (const float4*)(fcw + (long)g * 8);
      float4 u = s[0], v = s[1];
      sq = u.x*u.x + u.y*u.y + u.z*u.z + u.w*u.w
         + v.x*v.x + v.y*v.y + v.z*v.z + v.w*v.w;
      ushort4 o0, o1;
      o0.x = f32_to_bf16(u.x); o0.y = f32_to_bf16(u.y);
      o0.z = f32_to_bf16(u.z); o0.w = f32_to_bf16(u.w);
      o1.x = f32_to_bf16(v.x); o1.y = f32_to_bf16(v.y);
      o1.z = f32_to_bf16(v.z); o1.w = f32_to_bf16(v.w);
      ushort4* d = (ushort4*)(fcwb + (long)g * 8);
      d[0] = o0; d[1] = o1;
    }
    float tq = blk_reduce(sq, xs);
    if (t == 0) atomicAdd(&dacc[67], (double)tq);
  } else {
    int b = blockIdx.x - GATH_OFF2;
    int hi = h[b], ri = r[b];
    float s = 0.f, sq = 0.f;
    for (int i = t; i < 400; i += 256) {
      float v = (i < 200) ? ent[(long)hi * DD + i] : rel[(long)ri * DD + (i - 200)];
      x0[b * 400 + i] = v;
      s += v; sq += v * v;
    }
    float ts = blk_reduce(s, xs);
    float tq = blk_reduce(sq, xs);
    if (t == 0) {
      atomicAdd(&dacc[0], (double)ts);
      atomicAdd(&dacc[1], (double)tq);
    }
  }
}

// K2: bn0 + conv3x3 + conv_b -> yb bf16 [512 x 10368] (pre-bn1); bn1 stats (f32)
__global__ __launch_bounds__(256) void k_conv(const float* __restrict__ x0,
                       const float* __restrict__ convw, const float* __restrict__ convb,
                       const float* __restrict__ g0, const float* __restrict__ b0,
                       unsigned short* __restrict__ yb, double* dacc) {
  __shared__ float xs[400], wsm[288], cbs[32], ssum[32], ssq[32];
  __shared__ float a0s, s0s;
  int b = blockIdx.x, t = threadIdx.x;
  for (int i = t; i < 400; i += 256) xs[i] = x0[b * 400 + i];
  for (int i = t; i < 288; i += 256) wsm[i] = convw[i];
  if (t < 32) cbs[t] = convb[t];
  if (t == 0) {
    double m = dacc[0] / 204800.0;
    double v = dacc[1] / 204800.0 - m * m;
    float a = g0[0] * rsqrtf((float)v + BNEPS);
    a0s = a; s0s = b0[0] - (float)m * a;
  }
  __syncthreads();
  float a0 = a0s, s0 = s0s;
  for (int i = t; i < 400; i += 256) xs[i] = a0 * xs[i] + s0;
  __syncthreads();
  int c = t >> 3, sub = t & 7;
  const float* w = &wsm[c * 9];
  float cb = cbs[c];
  float s = 0.f, sq = 0.f;
  for (int e = sub; e < HW; e += 8) {
    int oh = e / 18, ow = e - oh * 18;
    const float* xp = &xs[oh * 20 + ow];
    float acc = cb
       + xp[0] * w[0] + xp[1] * w[1] + xp[2] * w[2]
       + xp[20] * w[3] + xp[21] * w[4] + xp[22] * w[5]
       + xp[40] * w[6] + xp[41] * w[7] + xp[42] * w[8];
    yb[(long)b * FCIN + c * HW + e] = f32_to_bf16(acc);
    s += acc; sq += acc * acc;
  }
  s += __shfl_xor(s, 1, 64); sq += __shfl_xor(sq, 1, 64);
  s += __shfl_xor(s, 2, 64); sq += __shfl_xor(sq, 2, 64);
  s += __shfl_xor(s, 4, 64); sq += __shfl_xor(sq, 4, 64);
  if (sub == 0) { ssum[c] = s; ssq[c] = sq; }
  __syncthreads();
  if (t < 32) {
    atomicAdd(&dacc[2 + t], (double)ssum[t]);
    atomicAdd(&dacc[34 + t], (double)ssq[t]);
  }
}

// K3: in-place bn1 + relu on yb (bf16)
__global__ __launch_bounds__(256) void k_prep(unsigned short* __restrict__ yb,
                                              const float* __restrict__ g1,
                                              const float* __restrict__ b1,
                                              const double* __restrict__ dacc) {
  __shared__ float a1s[32], sh1s[32];
  int t = threadIdx.x;
  if (t < 32) {
    double cnt = 512.0 * 324.0;
    double m = dacc[2 + t] / cnt, v = dacc[34 + t] / cnt - m * m;
    float a = g1[t] * rsqrtf((float)v + BNEPS);
    a1s[t] = a; sh1s[t] = b1[t] - (float)m * a;
  }
  __syncthreads();
  int g = blockIdx.x * 256 + t;          // 0..663551 (x8 elems)
  int row = g / 1296;
  int c8 = (g - row * 1296) * 8;
  unsigned short* p = yb + (long)row * FCIN + c8;
  ushort4 v0 = ((ushort4*)p)[0], v1 = ((ushort4*)p)[1];
  unsigned short e[8] = {v0.x, v0.y, v0.z, v0.w, v1.x, v1.y, v1.z, v1.w};
#pragma unroll
  for (int j = 0; j < 8; j++) {
    int c = (c8 + j) / HW;
    float f = a1s[c] * bf16_to_f32(e[j]) + sh1s[c];
    e[j] = f32_to_bf16(fmaxf(f, 0.f));
  }
  v0.x = e[0]; v0.y = e[1]; v0.z = e[2]; v0.w = e[3];
  v1.x = e[4]; v1.y = e[5]; v1.z = e[6]; v1.w = e[7];
  ((ushort4*)p)[0] = v0; ((ushort4*)p)[1] = v1;
}

// K4: FC GEMM via bf16 MFMA. 384 single-wave blocks = 12 kslices x (8 mt x 4 nt).
__global__ __launch_bounds__(64) void k_fc3(const unsigned short* __restrict__ yb,
                                            const unsigned short* __restrict__ fcwb,
                                            float* __restrict__ Cp) {
  int wid = blockIdx.x;             // 384 = 12 ks * 32 tiles
  int ks = wid >> 5, rem = wid & 31;
  int mt = rem >> 2, nt = rem & 3;
  int m0 = mt * 64, n0 = nt * 64;
  int lane = threadIdx.x;
  int quad = lane >> 4, lr = lane & 15;
  long kbeg = (long)ks * 864;       // 27 chunks of 32

  const unsigned short* arow[4];
  const unsigned short* brow[4];
#pragma unroll
  for (int mi = 0; mi < 4; mi++)
    arow[mi] = yb + (long)(m0 + mi * 16 + lr) * FCIN + kbeg + quad * 8;
#pragma unroll
  for (int ni = 0; ni < 4; ni++) {
    int d = n0 + ni * 16 + lr;
    if (d > DD - 1) d = DD - 1;
    brow[ni] = fcwb + (long)d * FCIN + kbeg + quad * 8;
  }

  floatx4 acc[4][4];
#pragma unroll
  for (int i = 0; i < 4; i++)
#pragma unroll
    for (int j = 0; j < 4; j++) acc[i][j] = (floatx4){0.f, 0.f, 0.f, 0.f};

  short8 sA[3][4], sB[3][4];
#pragma unroll
  for (int c = 0; c < 3; c++) {
#pragma unroll
    for (int mi = 0; mi < 4; mi++) sA[c][mi] = *(const short8*)(arow[mi] + c * 32);
#pragma unroll
    for (int ni = 0; ni < 4; ni++) sB[c][ni] = *(const short8*)(brow[ni] + c * 32);
  }
  for (int c3 = 0; c3 < 9; c3++) {
    int cc = c3 * 3;
#pragma unroll
    for (int j = 0; j < 3; j++) {
#pragma unroll
      for (int ni = 0; ni < 4; ni++)
#pragma unroll
        for (int mi = 0; mi < 4; mi++)
          acc[mi][ni] = __builtin_amdgcn_mfma_f32_16x16x32_bf16(sA[j][mi], sB[j][ni], acc[mi][ni], 0, 0, 0);
      int nxt = cc + j + 3;
      if (nxt < 27) {
#pragma unroll
        for (int mi = 0; mi < 4; mi++) sA[j][mi] = *(const short8*)(arow[mi] + nxt * 32);
#pragma unroll
        for (int ni = 0; ni < 4; ni++) sB[j][ni] = *(const short8*)(brow[ni] + nxt * 32);
      }
    }
  }

  float* out = Cp + (long)ks * (NB_B * DD);
#pragma unroll
  for (int ni = 0; ni < 4; ni++) {
    int d = n0 + ni * 16 + lr;
    if (d < DD) {
#pragma unroll
      for (int mi = 0; mi < 4; mi++) {
        int mbase = m0 + mi * 16 + quad * 4;
#pragma unroll
        for (int rg = 0; rg < 4; rg++)
          out[(mbase + rg) * DD + d] = acc[mi][ni][rg];
      }
    }
  }
}

// K4b (fused): reduce 12 partials -> Cfc AND bn2 stats -> a2/b2c.
__global__ void k_fcbn(const float* __restrict__ Cp, const float* __restrict__ fcb,
                       const float* __restrict__ g2, const float* __restrict__ b2,
                       float* __restrict__ Cfc, float* __restrict__ a2,
                       float* __restrict__ b2c) {
  int d = blockIdx.x, lane = threadIdx.x;
  float fb = fcb[d];
  float s = 0.f, sq = 0.f;
  for (int b = lane; b < NB_B; b += 64) {
    float v = 0.f;
#pragma unroll
    for (int p = 0; p < 12; p++) v += Cp[(long)p * (NB_B * DD) + b * DD + d];
    Cfc[b * DD + d] = v;
    float w = v + fb;
    s += w; sq += w * w;
  }
  for (int o = 32; o > 0; o >>= 1) { s += __shfl_down(s, o, 64); sq += __shfl_down(sq, o, 64); }
  if (lane == 0) {
    float m = s / 512.f, v = sq / 512.f - m * m;
    float a = g2[d] * rsqrtf(v + BNEPS);
    a2[d] = a; b2c[d] = b2[d] - m * a;
  }
}

// K6: x_final row: leaky_relu(bn2(fc)) -> xf f32 + xfb bf16(padded); fused pos-score
__global__ __launch_bounds__(256) void k_xfinal(const float* __restrict__ Cfc,
                         const float* __restrict__ fcb,
                         const float* __restrict__ a2, const float* __restrict__ b2c,
                         const float* __restrict__ ent, const float* __restrict__ bias,
                         const int* __restrict__ pos,
                         float* __restrict__ xf, unsigned short* __restrict__ xfb,
                         double* dacc) {
  __shared__ float xs[224];
  __shared__ float sbuf[8];
  int b = blockIdx.x, t = threadIdx.x;
  if (t < KP) {
    float xv = 0.f;
    if (t < DD) {
      float v = Cfc[b * DD + t] + fcb[t];
      xv = a2[t] * v + b2c[t];
      xv = xv >= 0.f ? xv : 0.01f * xv;
      xf[b * DD + t] = xv;
    }
    xfb[b * KP + t] = f32_to_bf16(xv);
    xs[t] = xv;
  }
  __syncthreads();
  int e = pos[b];
  float s = (t < DD) ? xs[t] * ent[(long)e * DD + t] : 0.f;
  float ts = blk_reduce(s, sbuf);
  if (t == 0) atomicAdd(&dacc[70], (double)(ts + bias[e]));
}

// ---------------------------------------------------------------------------
// K7: scores GEMM + fused softplus (R16-proven, 48us): runtime tile loop with
// ping-pong LDS, chunk-major entb, gload_lds staging, rotating 2-reg bias.
// Grid 1024 = 4 blocks/CU; 512 chunks x 2 row-halves; 6-7 tiles each.
// ---------------------------------------------------------------------------
static __device__ __forceinline__ void sc_compute10(
    const unsigned short* __restrict__ buf, const float (&bv)[2],
    const short8 (&af)[2][7], int quad, int lr, float& sp, float& ss) {
#pragma unroll
  for (int ni = 0; ni < 2; ni++) {
    float b1v = bv[ni];
    floatx4 acc0 = (floatx4){0.f, 0.f, 0.f, 0.f};
    floatx4 acc1 = (floatx4){0.f, 0.f, 0.f, 0.f};
#pragma unroll
    for (int kc = 0; kc < 7; kc++) {
      int c = kc * 4 + quad;
      short8 bsv = *(const short8*)(buf + c * 256 + (ni * 16 + lr) * 8);
      acc0 = __builtin_amdgcn_mfma_f32_16x16x32_bf16(af[0][kc], bsv, acc0, 0, 0, 0);
      acc1 = __builtin_amdgcn_mfma_f32_16x16x32_bf16(af[1][kc], bsv, acc1, 0, 0, 0);
    }
    // softplus in log2 domain: softplus(s) = ln2*(max(m1,0)+log2(1+2^-|m1|))
#pragma unroll
    for (int rg2 = 0; rg2 < 4; rg2++) {
      float s1 = acc0[rg2] + b1v;
      ss += s1;
      float m1 = s1 * 1.4426950408889634f;
      float e2 = __builtin_amdgcn_exp2f(-__builtin_fabsf(m1));
      sp += fmaxf(m1, 0.f) + __builtin_amdgcn_logf(1.f + e2);
    }
#pragma unroll
    for (int rg2 = 0; rg2 < 4; rg2++) {
      float s1 = acc1[rg2] + b1v;
      ss += s1;
      float m1 = s1 * 1.4426950408889634f;
      float e2 = __builtin_amdgcn_exp2f(-__builtin_fabsf(m1));
      sp += fmaxf(m1, 0.f) + __builtin_amdgcn_logf(1.f + e2);
    }
  }
}

__global__ __launch_bounds__(512) void k_scores11(
    const unsigned short* __restrict__ entb,  // tiled chunk-major bf16
    const unsigned short* __restrict__ xfb,   // [512][KP] bf16 bits
    const float* __restrict__ bias, double* dacc) {
  __shared__ unsigned short Bs[2][7168];      // 2 x 14 KB (one 32-ent tile)
  __shared__ float sbuf[8];
  int t = threadIdx.x;
  int wv = t >> 6, lane = t & 63;
  int quad = lane >> 4, lr = lane & 15;
  int b = blockIdx.x;
  int rh = b & 1;                  // row half: rows [rh*256, rh*256+256)
  int chunk = b >> 1;              // 512 chunks over 3126 tiles (32 ents each)
  int nt = (chunk < 54) ? 7 : 6;   // 54*7 + 458*6 = 3126
  int t0 = chunk * 6 + (chunk < 54 ? chunk : 54);

  short8 af[2][7];
#pragma unroll
  for (int mi = 0; mi < 2; mi++) {
    const unsigned short* ap =
        xfb + (size_t)(rh * 256 + wv * 32 + mi * 16 + lr) * KP + quad * 8;
#pragma unroll
    for (int kc = 0; kc < 7; kc++) af[mi][kc] = *(const short8*)(ap + kc * 32);
  }

  // async stage into runtime-selected buffer (LDS address, not reg array)
#define STAGE11(bufp, tile)                                                    \
  {                                                                            \
    _Pragma("unroll")                                                          \
    for (int i_ = 0; i_ < 2; i_++) {                                           \
      int s_ = wv * 2 + i_;                                                    \
      if (s_ < 14) {                                                           \
        const unsigned short* gp_ =                                            \
            entb + (size_t)(tile) * 7168 + s_ * 512 + lane * 8;                \
        __builtin_amdgcn_global_load_lds(                                      \
            (const __attribute__((address_space(1))) unsigned int*)gp_,       \
            (__attribute__((address_space(3))) unsigned int*)((bufp) + s_ * 512), \
            16, 0, 0);                                                         \
      }                                                                        \
    }                                                                          \
  }

  float sp = 0.f, ss = 0.f;
  float bv[2], bvn[2];

  STAGE11(&Bs[0][0], t0);
#pragma unroll
  for (int ni = 0; ni < 2; ni++) {
    int e = t0 * 32 + ni * 16 + lr;
    bv[ni] = (e < NE) ? bias[e] : 0.f;
  }
  __syncthreads();                      // drain first stage

  int cur = 0;
#pragma unroll 1
  for (int i = 0; i < nt; i++) {
    if (i + 1 < nt) {
      STAGE11(&Bs[cur ^ 1][0], t0 + i + 1);   // overlaps compute(i)
      int e0n = (t0 + i + 1) * 32 + lr;
      bvn[0] = (e0n < NE) ? bias[e0n] : 0.f;
      bvn[1] = (e0n + 16 < NE) ? bias[e0n + 16] : 0.f;
    }
    sc_compute10(&Bs[cur][0], bv, af, quad, lr, sp, ss);
    __syncthreads();                    // drains stage(i+1); frees Bs[cur]
    bv[0] = bvn[0]; bv[1] = bvn[1];
    cur ^= 1;
  }
#undef STAGE11

  sp *= 0.6931471805599453f;  // ln2
  float tsp = blk_reduce(sp, sbuf);
  float tss = blk_reduce(ss, sbuf);
  if (t == 0) {
    atomicAdd(&dacc[68], (double)tsp);
    atomicAdd(&dacc[69], (double)tss);
  }
}

// K8: final scalar (64 threads; also does conv_w L2 reduce).
// Subtract pad softplus constant: 512 rows x 32 pad entities x ln2
// (tile 3125 = pad rows, computed by both row-halves of chunk 511).
__global__ void k_final(const float* __restrict__ convw, const double* dacc, float* out) {
  int t = threadIdx.x;
  float sq = 0.f;
  for (int i = t; i < 288; i += 64) { float w = convw[i]; sq += w * w; }
  for (int o = 32; o > 0; o >>= 1) sq += __shfl_down(sq, o, 64);
  if (t == 0) {
    double SP = dacc[68] - 16384.0 * 0.6931471805599453;
    double S2 = dacc[69], S3 = dacc[70];
    double xy = S2 / (double)NE + 0.9 * S3;
    double kg = (SP - xy) / ((double)NB_B * (double)NE);
    double l2 = dacc[1] / 204800.0 + (double)sq / 576.0 + dacc[67] / 400.0;
    out[0] = (float)(kg + 1e-5 * l2);
  }
}

extern "C" void kernel_launch(void* const* d_in, const int* in_sizes, int n_in,
                              void* d_out, int out_size, void* d_ws, size_t ws_size,
                              hipStream_t stream) {
  const float* ent   = (const float*)d_in[0];
  const float* rel   = (const float*)d_in[1];
  const float* convw = (const float*)d_in[2];
  const float* convb = (const float*)d_in[3];
  const float* fcw   = (const float*)d_in[4];
  const float* fcb   = (const float*)d_in[5];
  const float* bias  = (const float*)d_in[6];
  const float* g0    = (const float*)d_in[7];
  const float* b0    = (const float*)d_in[8];
  const float* g1    = (const float*)d_in[9];
  const float* b1    = (const float*)d_in[10];
  const float* g2    = (const float*)d_in[11];
  const float* b2    = (const float*)d_in[12];
  const int*   h     = (const int*)d_in[13];
  const int*   r     = (const int*)d_in[14];
  const int*   pos   = (const int*)d_in[15];

  char* ws = (char*)d_ws;
  double* dacc = (double*)(ws + 0);                        // 8 KB
  float* a2  = (float*)(ws + 16384 + 256);                 // 200
  float* b2c = (float*)(ws + 16384 + 1056);                // 200
  float* x0  = (float*)(ws + 32768);                       // 512*400 f32      (819200 B)
  float* Cfc = (float*)(ws + 851968);                      // 512*200 f32      (409600 B)
  float* xf  = (float*)(ws + 1261568);                     // 512*200 f32      (409600 B)
  unsigned short* yb   = (unsigned short*)(ws + 1671168);  // 512*10368 bf16   (10616832 B)
  unsigned short* fcwb = (unsigned short*)(ws + 12288000); // 200*10368 bf16   (4147200 B)
  unsigned short* xfb  = (unsigned short*)(ws + 16435200); // 512*224 bf16     (229376 B)
  unsigned short* entb = (unsigned short*)(ws + 16664576); // 3126 tiles x 14336 B (44814336 B)
  float* Cp = (float*)(ws + 61507584);                     // 12*512*200 f32   (4915200 B) -> 66.4MB

  hipMemsetAsync(dacc, 0, 8192, stream);

  k_cvt<<<GATH_OFF2 + 512, 256, 0, stream>>>(ent, entb, fcw, fcwb, rel, h, r, x0, dacc);
  k_conv<<<512, 256, 0, stream>>>(x0, convw, convb, g0, b0, yb, dacc);
  k_prep<<<2592, 256, 0, stream>>>(yb, g1, b1, dacc);
  k_fc3<<<384, 64, 0, stream>>>(yb, fcwb, Cp);
  k_fcbn<<<200, 64, 0, stream>>>(Cp, fcb, g2, b2, Cfc, a2, b2c);
  k_xfinal<<<512, 256, 0, stream>>>(Cfc, fcb, a2, b2c, ent, bias, pos, xf, xfb, dacc);
  k_scores11<<<1024, 512, 0, stream>>>(entb, xfb, bias, dacc);
  k_final<<<1, 64, 0, stream>>>(convw, dacc, (float*)d_out);
}